// Round 1
// baseline (41053.949 us; speedup 1.0000x reference)
//
#include <hip/hip_runtime.h>
#include <cmath>

namespace {
constexpr int B_ = 64, TIN_ = 256, F_ = 64, H_ = 1024, TGT_ = 64, V_ = 32000;
constexpr long long VEC_SZ = (long long)B_ * TGT_ * V_;   // 131072000
constexpr long long HID_SZ = 2LL * B_ * H_;               // 131072
constexpr long long ATT_BASE = VEC_SZ + HID_SZ;
}

// ---------------------------------------------------------------------------
// Generic skinny GEMM: out[b][j] = sum_k A[b][k] * W[j][k]  (M=64 fixed)
// Supports 2 jobs sharing N (gi+gh for GRU gates) and split-K partial planes.
// direct mode (KS0+KS1==1): writes out + bias. Otherwise writes gbuf planes.
// Block tile: 64b x JT j.  Micro tile: 4b x MJ j (256 threads = 16bg x 16jg).
// ---------------------------------------------------------------------------
template<int JT, int MJ>
__global__ __launch_bounds__(256)
void gemm_k(const float* __restrict__ A0, int lda0, const float* __restrict__ W0, int ldw0, int K0, int KS0,
            const float* __restrict__ A1, int lda1, const float* __restrict__ W1, int ldw1, int K1, int KS1,
            const float* __restrict__ bias, float* __restrict__ outp, long long ldo,
            float* __restrict__ gbuf, int N, int njt)
{
    __shared__ float AT[32][68];        // [k][b], stride 68 (16B-aligned rows, odd-ish banks)
    __shared__ float WT[32][JT + 4];    // [k][j]
    const int tid = threadIdx.x;
    const int p  = blockIdx.x / njt;          // plane index (global over jobs)
    const int jt = blockIdx.x - p * njt;
    const int j0 = jt * JT;

    const float* A; int lda; const float* W; int ldw; int K, ks, KS;
    if (p < KS0) { A = A0; lda = lda0; W = W0; ldw = ldw0; K = K0; KS = KS0; ks = p; }
    else         { A = A1; lda = lda1; W = W1; ldw = ldw1; K = K1; KS = KS1; ks = p - KS0; }
    const int kslice = K / KS;
    const int kb = ks * kslice, ke = kb + kslice;

    const int bg = tid & 15, jg = tid >> 4;
    float acc[4][MJ];
#pragma unroll
    for (int i = 0; i < 4; ++i)
#pragma unroll
        for (int j = 0; j < MJ; ++j) acc[i][j] = 0.f;

    for (int k0 = kb; k0 < ke; k0 += 32) {
        // stage A: 64 rows x 32 k  (512 float4)
        for (int idx = tid; idx < 512; idx += 256) {
            int b = idx >> 3, kq = idx & 7;
            float4 a = *(const float4*)(A + (long long)b * lda + k0 + kq * 4);
            int kk = kq * 4;
            AT[kk + 0][b] = a.x; AT[kk + 1][b] = a.y; AT[kk + 2][b] = a.z; AT[kk + 3][b] = a.w;
        }
        // stage W: JT rows x 32 k
        for (int idx = tid; idx < JT * 8; idx += 256) {
            int j = idx >> 3, kq = idx & 7;
            float4 w = *(const float4*)(W + (long long)(j0 + j) * ldw + k0 + kq * 4);
            int kk = kq * 4;
            WT[kk + 0][j] = w.x; WT[kk + 1][j] = w.y; WT[kk + 2][j] = w.z; WT[kk + 3][j] = w.w;
        }
        __syncthreads();
#pragma unroll 8
        for (int k = 0; k < 32; ++k) {
            float4 a4 = *(const float4*)(&AT[k][bg * 4]);
            float av[4] = {a4.x, a4.y, a4.z, a4.w};
            float wv[MJ];
            *(float4*)(&wv[0]) = *(const float4*)(&WT[k][jg * MJ]);
            if (MJ == 8) *(float4*)(&wv[4]) = *(const float4*)(&WT[k][jg * MJ + 4]);
#pragma unroll
            for (int i = 0; i < 4; ++i)
#pragma unroll
                for (int j = 0; j < MJ; ++j) acc[i][j] += av[i] * wv[j];
        }
        __syncthreads();
    }

    const bool direct = (KS0 + KS1 == 1);
    const int b4 = bg * 4, jb = j0 + jg * MJ;
    if (direct) {
#pragma unroll
        for (int i = 0; i < 4; ++i) {
            float* op = outp + (long long)(b4 + i) * ldo + jb;
#pragma unroll
            for (int j = 0; j < MJ; ++j) op[j] = acc[i][j] + bias[jb + j];
        }
    } else {
#pragma unroll
        for (int i = 0; i < 4; ++i) {
            float* gp = gbuf + ((long long)p * 64 + (b4 + i)) * N + jb;
#pragma unroll
            for (int j = 0; j < MJ; ++j) gp[j] = acc[i][j];
        }
    }
}

// sum split-K planes + bias -> out[64][N]
__global__ __launch_bounds__(256)
void sumbias_k(const float* __restrict__ gbuf, int P, int N,
               const float* __restrict__ bias, float* __restrict__ outp)
{
    int idx = blockIdx.x * 256 + threadIdx.x;
    int b = idx / N, j = idx - b * N;
    float acc = bias[j];
    for (int p = 0; p < P; ++p) acc += gbuf[((long long)p * 64 + b) * N + j];
    outp[idx] = acc;
}

// GRU pointwise: consumes gate partial planes (gi planes [0,KSi), gh planes [KSi,P))
__global__ __launch_bounds__(256)
void gru_pw_k(const float* __restrict__ gbuf, int KSi, int P,
              const float* __restrict__ bih, const float* __restrict__ bhh,
              const float* __restrict__ hprev, float* __restrict__ hnew,
              float* __restrict__ out2, long long out2stride)
{
    int idx = blockIdx.x * 256 + threadIdx.x;   // 65536 = 64 * 1024
    int b = idx >> 10, jh = idx & 1023;
    float ir = 0, iz = 0, inn = 0, hr = 0, hz = 0, hn = 0;
    for (int p = 0; p < P; ++p) {
        const float* g = gbuf + ((long long)p * 64 + b) * 3072 + jh;
        float g0 = g[0], g1 = g[1024], g2 = g[2048];
        if (p < KSi) { ir += g0; iz += g1; inn += g2; }
        else         { hr += g0; hz += g1; hn += g2; }
    }
    ir += bih[jh]; iz += bih[1024 + jh]; inn += bih[2048 + jh];
    hr += bhh[jh]; hz += bhh[1024 + jh]; hn += bhh[2048 + jh];
    float r = 1.f / (1.f + expf(-(ir + hr)));
    float z = 1.f / (1.f + expf(-(iz + hz)));
    float n = tanhf(inn + r * hn);
    float hp = hprev[idx];
    float ho = (1.f - z) * n + z * hp;
    hnew[idx] = ho;
    if (out2) out2[(long long)b * out2stride + jh] = ho;
}

// Attention for one decode step. Block per batch row, 1024 threads.
// scores -> softmax -> context; writes context into comb_in[:, :1024] and
// attention weights into d_out attn column t.
__global__ __launch_bounds__(1024)
void attn_k(const float* __restrict__ q, const float* __restrict__ enc,
            float* __restrict__ att_out /* comb_in base */, float* __restrict__ attn_col)
{
    int b = blockIdx.x, tid = threadIdx.x;
    __shared__ float sq[H_];
    __shared__ float sc[TIN_];
    __shared__ float red[256];
    sq[tid] = q[b * H_ + tid];
    __syncthreads();
    int lane = tid & 63, wv = tid >> 6;     // 16 waves
    const float* eb = enc + (long long)b * TIN_ * H_;
    for (int i = wv; i < TIN_; i += 16) {
        const float* e = eb + (long long)i * H_;
        float acc = 0.f;
#pragma unroll
        for (int c = 0; c < H_ / 64; ++c) acc += e[c * 64 + lane] * sq[c * 64 + lane];
        for (int off = 32; off > 0; off >>= 1) acc += __shfl_down(acc, off, 64);
        if (lane == 0) sc[i] = acc;
    }
    __syncthreads();
    // softmax over 256 scores
    if (tid < 256) red[tid] = sc[tid];
    __syncthreads();
    for (int s = 128; s > 0; s >>= 1) { if (tid < s) red[tid] = fmaxf(red[tid], red[tid + s]); __syncthreads(); }
    float m = red[0];
    __syncthreads();
    float e = 0.f;
    if (tid < 256) { e = expf(sc[tid] - m); red[tid] = e; }
    __syncthreads();
    for (int s = 128; s > 0; s >>= 1) { if (tid < s) red[tid] += red[tid + s]; __syncthreads(); }
    float denom = red[0];
    __syncthreads();
    if (tid < 256) {
        float aw = e / denom;
        sc[tid] = aw;
        attn_col[(long long)b * TIN_ * TGT_ + (long long)tid * TGT_] = aw;
    }
    __syncthreads();
    float acc = 0.f;
#pragma unroll 4
    for (int i = 0; i < TIN_; ++i) acc += sc[i] * eb[(long long)i * H_ + tid];
    att_out[b * 2048 + tid] = acc;
}

// argmax over V logits (first-index tie-break, matching jnp.argmax) + embedding gather
__global__ __launch_bounds__(256)
void argmax_gather_k(const float* __restrict__ logits_base, const float* __restrict__ embed,
                     float* __restrict__ emb_buf)
{
    int b = blockIdx.x, tid = threadIdx.x;
    const float* p = logits_base + (long long)b * ((long long)TGT_ * V_);
    float best = -INFINITY; int bi = 0;
    for (int v = tid; v < V_; v += 256) {
        float x = p[v];
        if (x > best) { best = x; bi = v; }
    }
    __shared__ float bv[256]; __shared__ int bidx[256];
    bv[tid] = best; bidx[tid] = bi;
    __syncthreads();
    for (int s = 128; s > 0; s >>= 1) {
        if (tid < s) {
            float ov = bv[tid + s]; int oi = bidx[tid + s];
            if (ov > bv[tid] || (ov == bv[tid] && oi < bidx[tid])) { bv[tid] = ov; bidx[tid] = oi; }
        }
        __syncthreads();
    }
    int idx = bidx[0];
    for (int h = tid; h < H_; h += 256) emb_buf[b * H_ + h] = embed[(long long)idx * H_ + h];
}

extern "C" void kernel_launch(void* const* d_in, const int* in_sizes, int n_in,
                              void* d_out, int out_size, void* d_ws, size_t ws_size,
                              hipStream_t stream)
{
    (void)in_sizes; (void)n_in; (void)out_size; (void)ws_size;
    const float* x     = (const float*)d_in[0];
    const float* embed = (const float*)d_in[1];
    const float* eWih0 = (const float*)d_in[2];
    const float* eWhh0 = (const float*)d_in[3];
    const float* ebih0 = (const float*)d_in[4];
    const float* ebhh0 = (const float*)d_in[5];
    const float* eWih1 = (const float*)d_in[6];
    const float* eWhh1 = (const float*)d_in[7];
    const float* ebih1 = (const float*)d_in[8];
    const float* ebhh1 = (const float*)d_in[9];
    const float* dWih0 = (const float*)d_in[10];
    const float* dWhh0 = (const float*)d_in[11];
    const float* dbih0 = (const float*)d_in[12];
    const float* dbhh0 = (const float*)d_in[13];
    const float* dWih1 = (const float*)d_in[14];
    const float* dWhh1 = (const float*)d_in[15];
    const float* dbih1 = (const float*)d_in[16];
    const float* dbhh1 = (const float*)d_in[17];
    const float* Wq    = (const float*)d_in[18];
    const float* bq    = (const float*)d_in[19];
    const float* Wc    = (const float*)d_in[20];
    const float* bc    = (const float*)d_in[21];
    const float* Wfc   = (const float*)d_in[22];
    const float* bfc   = (const float*)d_in[23];
    float* out = (float*)d_out;

    // workspace layout (floats); total ~18.94M floats (~75.8 MB)
    float* ws = (float*)d_ws;
    float* enc_outs = ws;                                   // 16777216
    float* h0[2] = { ws + 16777216, ws + 16777216 + 65536 };
    float* h1[2] = { ws + 16908288, ws + 16908288 + 65536 };
    float* emb_buf = ws + 17039360;                         // 65536
    float* qbuf    = ws + 17104896;                         // 65536
    float* comb_in = ws + 17170432;                         // 131072 (64 x 2048)
    float* comb    = ws + 17301504;                         // 65536
    float* gbuf    = ws + 17367040;                         // 1572864 (8 planes x 64 x 3072)

    hipMemsetAsync(h0[0], 0, 65536 * 4, stream);
    hipMemsetAsync(h1[0], 0, 65536 * 4, stream);
    hipMemsetAsync(emb_buf, 0, 65536 * 4, stream);          // embed[0] row is zeros

    int par = 0;
    // ---------------- encoder: 256 steps ----------------
    for (int t = 0; t < TIN_; ++t) {
        // layer0: gi (K=64, KS=2) + gh (K=1024, KS=4) -> 6 planes
        gemm_k<64, 4><<<dim3(48 * 6), 256, 0, stream>>>(
            x + t * F_, TIN_ * F_, eWih0, F_, F_, 2,
            h0[par], H_, eWhh0, H_, H_, 4,
            nullptr, nullptr, 0, gbuf, 3072, 48);
        gru_pw_k<<<dim3(256), 256, 0, stream>>>(gbuf, 2, 6, ebih0, ebhh0,
                                                h0[par], h0[par ^ 1], nullptr, 0);
        // layer1: gi (K=1024, KS=4) + gh (K=1024, KS=4) -> 8 planes
        gemm_k<64, 4><<<dim3(48 * 8), 256, 0, stream>>>(
            h0[par ^ 1], H_, eWih1, H_, H_, 4,
            h1[par], H_, eWhh1, H_, H_, 4,
            nullptr, nullptr, 0, gbuf, 3072, 48);
        gru_pw_k<<<dim3(256), 256, 0, stream>>>(gbuf, 4, 8, ebih1, ebhh1,
                                                h1[par], h1[par ^ 1],
                                                enc_outs + t * H_, (long long)TIN_ * H_);
        par ^= 1;
    }

    // ---------------- decoder: 64 steps ----------------
    for (int t = 0; t < TGT_; ++t) {
        gemm_k<64, 4><<<dim3(48 * 8), 256, 0, stream>>>(
            emb_buf, H_, dWih0, H_, H_, 4,
            h0[par], H_, dWhh0, H_, H_, 4,
            nullptr, nullptr, 0, gbuf, 3072, 48);
        gru_pw_k<<<dim3(256), 256, 0, stream>>>(gbuf, 4, 8, dbih0, dbhh0,
                                                h0[par], h0[par ^ 1], nullptr, 0);
        gemm_k<64, 4><<<dim3(48 * 8), 256, 0, stream>>>(
            h0[par ^ 1], H_, dWih1, H_, H_, 4,
            h1[par], H_, dWhh1, H_, H_, 4,
            nullptr, nullptr, 0, gbuf, 3072, 48);
        gru_pw_k<<<dim3(256), 256, 0, stream>>>(gbuf, 4, 8, dbih1, dbhh1,
                                                h1[par], h1[par ^ 1],
                                                comb_in + H_, 2 * H_);   // also fill concat 2nd half
        // q = h1' @ Wq^T + bq  (split-K 4 + sum)
        gemm_k<64, 4><<<dim3(16 * 4), 256, 0, stream>>>(
            h1[par ^ 1], H_, Wq, H_, H_, 4,
            nullptr, 0, nullptr, 0, 1, 0,
            nullptr, nullptr, 0, gbuf, 1024, 16);
        sumbias_k<<<dim3(256), 256, 0, stream>>>(gbuf, 4, 1024, bq, qbuf);
        // attention: context -> comb_in[:, :1024], weights -> attn column t
        attn_k<<<dim3(64), 1024, 0, stream>>>(qbuf, enc_outs, comb_in, out + ATT_BASE + t);
        // comb = [att, h1'] @ Wc^T + bc  (K=2048, split-K 8 + sum)
        gemm_k<64, 4><<<dim3(16 * 8), 256, 0, stream>>>(
            comb_in, 2 * H_, Wc, 2 * H_, 2 * H_, 8,
            nullptr, 0, nullptr, 0, 1, 0,
            nullptr, nullptr, 0, gbuf, 1024, 16);
        sumbias_k<<<dim3(256), 256, 0, stream>>>(gbuf, 8, 1024, bc, comb);
        // logits = comb @ Wfc^T + bfc, direct into d_out vec slice
        gemm_k<128, 8><<<dim3(250), 256, 0, stream>>>(
            comb, H_, Wfc, H_, H_, 1,
            nullptr, 0, nullptr, 0, 1, 0,
            bfc, out + (long long)t * V_, (long long)TGT_ * V_, nullptr, V_, 250);
        // argmax + next-token embedding gather
        argmax_gather_k<<<dim3(64), 256, 0, stream>>>(out + (long long)t * V_, embed, emb_buf);
        par ^= 1;
    }

    // final hidden state [2, B, H]
    hipMemcpyAsync(out + VEC_SZ, h0[0], 65536 * 4, hipMemcpyDeviceToDevice, stream);
    hipMemcpyAsync(out + VEC_SZ + 65536, h1[0], 65536 * 4, hipMemcpyDeviceToDevice, stream);
}